// Round 3
// baseline (1368.207 us; speedup 1.0000x reference)
//
#include <hip/hip_runtime.h>

// ---------- types ----------
typedef __bf16 bf16;
typedef __attribute__((ext_vector_type(8))) __bf16 bf16x8;
typedef __attribute__((ext_vector_type(4))) float f32x4;

#define T_SEQ 1024
#define D_MODEL 512
#define N_INT 2048
#define NHEADS 8
#define IN_DIM 372
#define OUT_DIM 186

__device__ inline void gld16(const bf16* g, bf16* l) {
  __builtin_amdgcn_global_load_lds((const __attribute__((address_space(1))) void*)g,
                                   (__attribute__((address_space(3))) void*)l, 16, 0, 0);
}

// block-wide sum of two values (256 threads)
__device__ inline void block_sum2(float& a, float& b, float* red) {
#pragma unroll
  for (int o = 32; o > 0; o >>= 1) {
    a += __shfl_down(a, o, 64);
    b += __shfl_down(b, o, 64);
  }
  __syncthreads();
  if ((threadIdx.x & 63) == 0) {
    int w = threadIdx.x >> 6;
    red[2 * w] = a;
    red[2 * w + 1] = b;
  }
  __syncthreads();
  a = red[0] + red[2] + red[4] + red[6];
  b = red[1] + red[3] + red[5] + red[7];
}

// ---------- transpose + fp32->bf16 convert:  out[c][r] = in[r][c], per z-matrix ----------
__global__ __launch_bounds__(256) void transpose_cvt(const float* __restrict__ in,
                                                     bf16* __restrict__ out,
                                                     int rows, int cols) {
  __shared__ float tile[32][33];
  size_t zoff = (size_t)blockIdx.z * rows * cols;
  in += zoff;
  out += zoff;
  int c0 = blockIdx.x * 32, r0 = blockIdx.y * 32;
#pragma unroll
  for (int i = threadIdx.y; i < 32; i += 8)
    tile[i][threadIdx.x] = in[(size_t)(r0 + i) * cols + c0 + threadIdx.x];
  __syncthreads();
#pragma unroll
  for (int i = threadIdx.y; i < 32; i += 8)
    out[(size_t)(c0 + i) * rows + r0 + threadIdx.x] = (bf16)tile[threadIdx.x][i];
}

// ---------- RoPE tables: cos/sin[t][i], freqs[i] = 2^(-16*i/1024) ----------
__global__ __launch_bounds__(256) void rope_tables(float* __restrict__ ct, float* __restrict__ st) {
  int t = blockIdx.x;
  for (int i = threadIdx.x; i < 1024; i += 256) {
    float ph = (float)t * exp2f(-16.0f * (float)i * (1.0f / 1024.0f));
    ct[(size_t)t * 1024 + i] = cosf(ph);
    st[(size_t)t * 1024 + i] = sinf(ph);
  }
}

// ---------- RoPE apply (per batch): qr = hsp*cos + rotate_half(hsp)*sin ----------
// hsp/qr: [8 heads][1024 t][2048 n]
__global__ __launch_bounds__(256) void rope_apply(const bf16* __restrict__ hsp,
                                                  const float* __restrict__ ct,
                                                  const float* __restrict__ st,
                                                  bf16* __restrict__ qr) {
  size_t row = (size_t)blockIdx.x * 2 + (threadIdx.x >> 7);  // (h,t) row, 8192 rows
  int i = threadIdx.x & 127;
  int t = (int)(row & (T_SEQ - 1));
  const bf16* src = hsp + row * N_INT;
  bf16* dst = qr + row * N_INT;
  int n1 = i * 8;
  bf16x8 x1 = *(const bf16x8*)(src + n1);
  bf16x8 x2 = *(const bf16x8*)(src + n1 + 1024);
  const float* cp = ct + (size_t)t * 1024 + n1;
  const float* sp = st + (size_t)t * 1024 + n1;
  bf16x8 o1, o2;
#pragma unroll
  for (int j = 0; j < 8; ++j) {
    float c = cp[j], s = sp[j];
    float a = (float)x1[j], b = (float)x2[j];
    o1[j] = (bf16)(a * c - b * s);
    o2[j] = (bf16)(b * c + a * s);
  }
  *(bf16x8*)(dst + n1) = o1;
  *(bf16x8*)(dst + n1 + 1024) = o2;
}

// ---------- input projection + LN:  h = LN(x@Wi + bi); writes h fp32, h bf16, hT bf16 ----------
__global__ __launch_bounds__(256) void in_proj(const float* __restrict__ x,
                                               const float* __restrict__ Wi,
                                               const float* __restrict__ bi,
                                               float* __restrict__ h, bf16* __restrict__ hbf,
                                               bf16* __restrict__ hT) {
  __shared__ float xs[4][IN_DIM];
  __shared__ float red[8];
  int r0 = blockIdx.x * 4;
  int tid = threadIdx.x;
  for (int idx = tid; idx < 4 * IN_DIM; idx += 256) {
    int rr = idx / IN_DIM, k = idx % IN_DIM;
    xs[rr][k] = x[(size_t)(r0 + rr) * IN_DIM + k];
  }
  __syncthreads();
  float acc[4][2] = {};
  for (int k = 0; k < IN_DIM; ++k) {
    float w0 = Wi[(size_t)k * 512 + tid];
    float w1 = Wi[(size_t)k * 512 + tid + 256];
#pragma unroll
    for (int rr = 0; rr < 4; ++rr) {
      acc[rr][0] += xs[rr][k] * w0;
      acc[rr][1] += xs[rr][k] * w1;
    }
  }
  float b0 = bi[tid], b1 = bi[tid + 256];
  for (int rr = 0; rr < 4; ++rr) {
    float v0 = acc[rr][0] + b0, v1 = acc[rr][1] + b1;
    float s = v0 + v1, s2 = v0 * v0 + v1 * v1;
    block_sum2(s, s2, red);
    float mean = s * (1.f / 512.f);
    float var = s2 * (1.f / 512.f) - mean * mean;
    float rs = rsqrtf(var + 1e-5f);
    float o0 = (v0 - mean) * rs, o1 = (v1 - mean) * rs;
    int r = r0 + rr;
    h[(size_t)r * 512 + tid] = o0;
    h[(size_t)r * 512 + tid + 256] = o1;
    hbf[(size_t)r * 512 + tid] = (bf16)o0;
    hbf[(size_t)r * 512 + tid + 256] = (bf16)o1;
    int b = r >> 10, t = r & (T_SEQ - 1);
    hT[((size_t)b * 512 + tid) * T_SEQ + t] = (bf16)o0;
    hT[((size_t)b * 512 + tid + 256) * T_SEQ + t] = (bf16)o1;
  }
}

// ---------- in-place LN on bf16 rows of 512 ----------
__global__ __launch_bounds__(256) void ln_rows(bf16* __restrict__ io) {
  __shared__ float red[8];
  size_t r = blockIdx.x;
  int tid = threadIdx.x;
  float v0 = (float)io[r * 512 + tid], v1 = (float)io[r * 512 + tid + 256];
  float s = v0 + v1, s2 = v0 * v0 + v1 * v1;
  block_sum2(s, s2, red);
  float mean = s * (1.f / 512.f);
  float var = s2 * (1.f / 512.f) - mean * mean;
  float rs = rsqrtf(var + 1e-5f);
  io[r * 512 + tid] = (bf16)((v0 - mean) * rs);
  io[r * 512 + tid + 256] = (bf16)((v1 - mean) * rs);
}

// ---------- h = LN(h_res + LN(z)); writes h fp32, h bf16, hT bf16 ----------
__global__ __launch_bounds__(256) void ln_double(const float* __restrict__ zin,
                                                 float* __restrict__ h, bf16* __restrict__ hbf,
                                                 bf16* __restrict__ hT) {
  __shared__ float red[8];
  size_t r = blockIdx.x;
  int tid = threadIdx.x;
  float z0 = zin[r * 512 + tid], z1 = zin[r * 512 + tid + 256];
  float s = z0 + z1, s2 = z0 * z0 + z1 * z1;
  block_sum2(s, s2, red);
  float m1 = s * (1.f / 512.f);
  float v1_ = s2 * (1.f / 512.f) - m1 * m1;
  float rs1 = rsqrtf(v1_ + 1e-5f);
  float a0 = (z0 - m1) * rs1 + h[r * 512 + tid];
  float a1 = (z1 - m1) * rs1 + h[r * 512 + tid + 256];
  s = a0 + a1;
  s2 = a0 * a0 + a1 * a1;
  block_sum2(s, s2, red);
  float m2 = s * (1.f / 512.f);
  float v2_ = s2 * (1.f / 512.f) - m2 * m2;
  float rs2 = rsqrtf(v2_ + 1e-5f);
  float o0 = (a0 - m2) * rs2, o1 = (a1 - m2) * rs2;
  h[r * 512 + tid] = o0;
  h[r * 512 + tid + 256] = o1;
  hbf[r * 512 + tid] = (bf16)o0;
  hbf[r * 512 + tid + 256] = (bf16)o1;
  int b = (int)(r >> 10), t = (int)(r & (T_SEQ - 1));
  hT[((size_t)b * 512 + tid) * T_SEQ + t] = (bf16)o0;
  hT[((size_t)b * 512 + tid + 256) * T_SEQ + t] = (bf16)o1;
}

// ---------- out = h @ Wo + bo ----------
__global__ __launch_bounds__(192) void out_proj(const float* __restrict__ h,
                                                const float* __restrict__ Wo,
                                                const float* __restrict__ bo,
                                                float* __restrict__ out) {
  __shared__ float hs[4][512];
  int r0 = blockIdx.x * 4, tid = threadIdx.x;
  for (int idx = tid; idx < 4 * 512; idx += 192) hs[idx >> 9][idx & 511] = h[(size_t)r0 * 512 + idx];
  __syncthreads();
  if (tid < OUT_DIM) {
    float bb = bo[tid];
    float acc[4] = {bb, bb, bb, bb};
    for (int k = 0; k < 512; ++k) {
      float w = Wo[(size_t)k * OUT_DIM + tid];
#pragma unroll
      for (int rr = 0; rr < 4; ++rr) acc[rr] += hs[rr][k] * w;
    }
#pragma unroll
    for (int rr = 0; rr < 4; ++rr) out[(size_t)(r0 + rr) * OUT_DIM + tid] = acc[rr];
  }
}

// ---------- generic 128x128 bf16 MFMA GEMM, C = A @ Bt^T, double-buffered LDS ----------
// MODE 0: hsp = relu(hbf_b @ encT^T)        z = head
// MODE 1: S   = causal_mask(qr @ qr^T)      z = head, compacted lower-triangle grid
// MODE 2: ykv = bf16(S @ hT_b^T)            z = head, K bounded causally
// MODE 3: xy  = relu(ykv @ encvT^T) * hsp   z = head, writes token-major layout
// MODE 4: z  += xy @ decT^T                 z = split-K chunk (atomicAdd)
template <int MODE>
__global__ __launch_bounds__(256, 2) void gemm_bt(const bf16* __restrict__ Abase,
                                                  const bf16* __restrict__ Bbase,
                                                  const bf16* __restrict__ aux,
                                                  float* __restrict__ fout,
                                                  bf16* __restrict__ bout) {
  int bi = blockIdx.x, bj = blockIdx.y;
  const int bz = blockIdx.z;
  if constexpr (MODE == 1) {
    // compact lower-triangle mapping: l -> (bi,bj), bj<=bi
    int l = blockIdx.x;
    float f = sqrtf(8.0f * (float)l + 1.0f);
    bi = (int)((f - 1.0f) * 0.5f);
    while ((bi + 1) * (bi + 2) / 2 <= l) ++bi;
    while (bi * (bi + 1) / 2 > l) --bi;
    bj = l - bi * (bi + 1) / 2;
  }

  const bf16* A;
  const bf16* Bt;
  int lda, ldb, kend;
  if constexpr (MODE == 0) {
    A = Abase; lda = 512;
    Bt = Bbase + (size_t)bz * N_INT * 512; ldb = 512;
    kend = 512;
  } else if constexpr (MODE == 1) {
    A = Abase + (size_t)bz * T_SEQ * N_INT; lda = N_INT;
    Bt = A; ldb = N_INT;
    kend = N_INT;
  } else if constexpr (MODE == 2) {
    A = Abase + (size_t)bz * T_SEQ * T_SEQ; lda = T_SEQ;
    Bt = Bbase; ldb = T_SEQ;
    kend = (bi + 1) * 128;  // causal bound
  } else if constexpr (MODE == 3) {
    A = Abase + (size_t)bz * T_SEQ * 512; lda = 512;
    Bt = Bbase + (size_t)bz * N_INT * 512; ldb = 512;
    kend = 512;
  } else {
    A = Abase + (size_t)bz * 2048; lda = 16384;  // split-K chunk of 2048
    Bt = Bbase + (size_t)bz * 2048; ldb = 16384;
    kend = 2048;
  }

  const int tid = threadIdx.x;
  const int srow = tid >> 2, scol = (tid & 3) * 8;
  const bf16* ag = A + (size_t)(bi * 128 + srow) * lda + scol;
  const bf16* bg = Bt + (size_t)(bj * 128 + srow) * ldb + scol;
  const size_t a64 = (size_t)64 * lda, b64 = (size_t)64 * ldb;

  __shared__ __align__(16) bf16 As[2][128 * 32];
  __shared__ __align__(16) bf16 Bs[2][128 * 32];
  const int so = tid * 8;

  const int lane = tid & 63, wid = tid >> 6;
  const int wr = wid >> 1, wc = wid & 1;
  const int fr = lane & 15, fg = lane >> 4;
  const int arow0 = (wr * 64 + fr) * 32 + fg * 8;
  const int brow0 = (wc * 64 + fr) * 32 + fg * 8;

  f32x4 acc[4][4] = {};

  // prologue: stage tile 0 into buffer 0
  gld16(ag, &As[0][so]);
  gld16(ag + a64, &As[0][2048 + so]);
  gld16(bg, &Bs[0][so]);
  gld16(bg + b64, &Bs[0][2048 + so]);
  __syncthreads();  // vmcnt(0) drain + barrier: tile 0 resident

  int cur = 0;
  for (int kk = 0; kk < kend; kk += 32) {
    // issue next-tile stage into the other buffer (latency hides under MFMA)
    const int nxt = kk + 32;
    if (nxt < kend) {
      const int nb = cur ^ 1;
      gld16(ag + nxt, &As[nb][so]);
      gld16(ag + a64 + nxt, &As[nb][2048 + so]);
      gld16(bg + nxt, &Bs[nb][so]);
      gld16(bg + b64 + nxt, &Bs[nb][2048 + so]);
    }
    // compute current tile
    bf16x8 af[4], bfr[4];
#pragma unroll
    for (int m = 0; m < 4; ++m) af[m] = *(const bf16x8*)(&As[cur][arow0 + m * 512]);
#pragma unroll
    for (int n = 0; n < 4; ++n) bfr[n] = *(const bf16x8*)(&Bs[cur][brow0 + n * 512]);
#pragma unroll
    for (int m = 0; m < 4; ++m)
#pragma unroll
      for (int n = 0; n < 4; ++n)
        acc[m][n] = __builtin_amdgcn_mfma_f32_16x16x32_bf16(af[m], bfr[n], acc[m][n], 0, 0, 0);
    __syncthreads();  // drains vmcnt(0): next tile landed while MFMAs ran
    cur ^= 1;
  }

#pragma unroll
  for (int m = 0; m < 4; ++m) {
#pragma unroll
    for (int n = 0; n < 4; ++n) {
#pragma unroll
      for (int j = 0; j < 4; ++j) {
        int r = bi * 128 + wr * 64 + m * 16 + fg * 4 + j;
        int c = bj * 128 + wc * 64 + n * 16 + fr;
        float v = acc[m][n][j];
        if constexpr (MODE == 0) {
          v = fmaxf(v, 0.f);
          bout[((size_t)bz * T_SEQ + r) * N_INT + c] = (bf16)v;
        } else if constexpr (MODE == 1) {
          bout[(size_t)bz * T_SEQ * T_SEQ + (size_t)r * T_SEQ + c] = (bf16)(c < r ? v : 0.f);
        } else if constexpr (MODE == 2) {
          bout[((size_t)bz * T_SEQ + r) * 512 + c] = (bf16)v;
        } else if constexpr (MODE == 3) {
          v = fmaxf(v, 0.f);
          float g = (float)aux[((size_t)bz * T_SEQ + r) * N_INT + c];
          bout[(size_t)r * 16384 + (size_t)bz * N_INT + c] = (bf16)(v * g);
        } else {
          atomicAdd(fout + (size_t)r * 512 + c, v);
        }
      }
    }
  }
}

// ---------- launch ----------
extern "C" void kernel_launch(void* const* d_in, const int* in_sizes, int n_in,
                              void* d_out, int out_size, void* d_ws, size_t ws_size,
                              hipStream_t stream) {
  const float* x = (const float*)d_in[0];
  const float* Wi = (const float*)d_in[1];
  const float* bi = (const float*)d_in[2];
  const float* enc = (const float*)d_in[3];
  const float* encv = (const float*)d_in[4];
  const float* dec = (const float*)d_in[5];
  const float* Wo = (const float*)d_in[6];
  const float* bo = (const float*)d_in[7];
  float* out = (float*)d_out;

  // workspace budget: 156 MiB. If the harness scratch is smaller, bail out
  // cleanly (output stays zero -> clean absmax failure, not a GPU fault).
  const size_t NEED = 163577856;
  if (ws_size < NEED) return;

  char* w = (char*)d_ws;
  auto alloc = [&](size_t bytes) {
    char* p = w;
    w += (bytes + 255) & ~(size_t)255;
    return p;
  };
  bf16* encT = (bf16*)alloc((size_t)NHEADS * N_INT * 512 * 2);   // [h][n][d] 16M
  bf16* encvT = (bf16*)alloc((size_t)NHEADS * N_INT * 512 * 2);  // [h][n][d] 16M
  bf16* decT = (bf16*)alloc((size_t)512 * 16384 * 2);            // [d][hn]   16M
  float* cost = (float*)alloc((size_t)T_SEQ * 1024 * 4);         // 4M
  float* sint = (float*)alloc((size_t)T_SEQ * 1024 * 4);         // 4M
  float* h = (float*)alloc((size_t)2048 * 512 * 4);              // 4M
  bf16* hbf = (bf16*)alloc((size_t)2048 * 512 * 2);              // 2M
  bf16* hT = (bf16*)alloc((size_t)2048 * 512 * 2);               // [b][d][t] 2M
  bf16* hsp = (bf16*)alloc((size_t)NHEADS * T_SEQ * N_INT * 2);  // per-batch [h][t][n] 32M
  bf16* qr = (bf16*)alloc((size_t)NHEADS * T_SEQ * N_INT * 2);   // per-batch; reused as xy 32M
  bf16* S = (bf16*)alloc((size_t)NHEADS * T_SEQ * T_SEQ * 2);    // per-batch 16M
  bf16* ykv = (bf16*)alloc((size_t)NHEADS * T_SEQ * 512 * 2);    // per-batch 8M
  float* zbuf = (float*)alloc((size_t)2048 * 512 * 4);           // 4M

  transpose_cvt<<<dim3(64, 16, 8), dim3(32, 8), 0, stream>>>(enc, encT, 512, N_INT);
  transpose_cvt<<<dim3(64, 16, 8), dim3(32, 8), 0, stream>>>(encv, encvT, 512, N_INT);
  transpose_cvt<<<dim3(16, 512, 1), dim3(32, 8), 0, stream>>>(dec, decT, 16384, 512);
  rope_tables<<<1024, 256, 0, stream>>>(cost, sint);
  in_proj<<<512, 256, 0, stream>>>(x, Wi, bi, h, hbf, hT);

  for (int L = 0; L < 3; ++L) {
    hipMemsetAsync(zbuf, 0, (size_t)2048 * 512 * 4, stream);
    for (int b = 0; b < 2; ++b) {
      const bf16* hbf_b = hbf + (size_t)b * T_SEQ * 512;
      const bf16* hT_b = hT + (size_t)b * 512 * T_SEQ;
      float* zbuf_b = zbuf + (size_t)b * T_SEQ * 512;
      gemm_bt<0><<<dim3(8, 16, 8), 256, 0, stream>>>(hbf_b, encT, nullptr, nullptr, hsp);
      rope_apply<<<4096, 256, 0, stream>>>(hsp, cost, sint, qr);
      gemm_bt<1><<<dim3(36, 1, 8), 256, 0, stream>>>(qr, nullptr, nullptr, nullptr, S);
      gemm_bt<2><<<dim3(8, 4, 8), 256, 0, stream>>>(S, hT_b, nullptr, nullptr, ykv);
      ln_rows<<<8192, 256, 0, stream>>>(ykv);
      gemm_bt<3><<<dim3(8, 16, 8), 256, 0, stream>>>(ykv, encvT, hsp, nullptr, qr);
      gemm_bt<4><<<dim3(8, 4, 8), 256, 0, stream>>>(qr, decT, nullptr, zbuf_b, nullptr);
    }
    ln_double<<<2048, 256, 0, stream>>>(zbuf, h, hbf, hT);
  }
  out_proj<<<512, 192, 0, stream>>>(h, Wo, bo, out);
}

// Round 4
// 1126.074 us; speedup vs baseline: 1.2150x; 1.2150x over previous
//
#include <hip/hip_runtime.h>

// ---------- types ----------
typedef __bf16 bf16;
typedef __attribute__((ext_vector_type(8))) __bf16 bf16x8;
typedef __attribute__((ext_vector_type(4))) float f32x4;

#define T_SEQ 1024
#define D_MODEL 512
#define N_INT 2048
#define NHEADS 8
#define IN_DIM 372
#define OUT_DIM 186

__device__ inline void gld16(const bf16* g, bf16* l) {
  __builtin_amdgcn_global_load_lds((const __attribute__((address_space(1))) void*)g,
                                   (__attribute__((address_space(3))) void*)l, 16, 0, 0);
}

// block-wide sum of two values (256 threads)
__device__ inline void block_sum2(float& a, float& b, float* red) {
#pragma unroll
  for (int o = 32; o > 0; o >>= 1) {
    a += __shfl_down(a, o, 64);
    b += __shfl_down(b, o, 64);
  }
  __syncthreads();
  if ((threadIdx.x & 63) == 0) {
    int w = threadIdx.x >> 6;
    red[2 * w] = a;
    red[2 * w + 1] = b;
  }
  __syncthreads();
  a = red[0] + red[2] + red[4] + red[6];
  b = red[1] + red[3] + red[5] + red[7];
}

// ---------- transpose + fp32->bf16 convert:  out[c][r] = in[r][c], per z-matrix ----------
__global__ __launch_bounds__(256) void transpose_cvt(const float* __restrict__ in,
                                                     bf16* __restrict__ out,
                                                     int rows, int cols) {
  __shared__ float tile[32][33];
  size_t zoff = (size_t)blockIdx.z * rows * cols;
  in += zoff;
  out += zoff;
  int c0 = blockIdx.x * 32, r0 = blockIdx.y * 32;
#pragma unroll
  for (int i = threadIdx.y; i < 32; i += 8)
    tile[i][threadIdx.x] = in[(size_t)(r0 + i) * cols + c0 + threadIdx.x];
  __syncthreads();
#pragma unroll
  for (int i = threadIdx.y; i < 32; i += 8)
    out[(size_t)(c0 + i) * rows + r0 + threadIdx.x] = (bf16)tile[threadIdx.x][i];
}

// ---------- RoPE tables ----------
__global__ __launch_bounds__(256) void rope_tables(float* __restrict__ ct, float* __restrict__ st) {
  int t = blockIdx.x;
  for (int i = threadIdx.x; i < 1024; i += 256) {
    float ph = (float)t * exp2f(-16.0f * (float)i * (1.0f / 1024.0f));
    ct[(size_t)t * 1024 + i] = cosf(ph);
    st[(size_t)t * 1024 + i] = sinf(ph);
  }
}

// ---------- RoPE apply (per batch) ----------
__global__ __launch_bounds__(256) void rope_apply(const bf16* __restrict__ hsp,
                                                  const float* __restrict__ ct,
                                                  const float* __restrict__ st,
                                                  bf16* __restrict__ qr) {
  size_t row = (size_t)blockIdx.x * 2 + (threadIdx.x >> 7);
  int i = threadIdx.x & 127;
  int t = (int)(row & (T_SEQ - 1));
  const bf16* src = hsp + row * N_INT;
  bf16* dst = qr + row * N_INT;
  int n1 = i * 8;
  bf16x8 x1 = *(const bf16x8*)(src + n1);
  bf16x8 x2 = *(const bf16x8*)(src + n1 + 1024);
  const float* cp = ct + (size_t)t * 1024 + n1;
  const float* sp = st + (size_t)t * 1024 + n1;
  bf16x8 o1, o2;
#pragma unroll
  for (int j = 0; j < 8; ++j) {
    float c = cp[j], s = sp[j];
    float a = (float)x1[j], b = (float)x2[j];
    o1[j] = (bf16)(a * c - b * s);
    o2[j] = (bf16)(b * c + a * s);
  }
  *(bf16x8*)(dst + n1) = o1;
  *(bf16x8*)(dst + n1 + 1024) = o2;
}

// ---------- input projection + LN ----------
__global__ __launch_bounds__(256) void in_proj(const float* __restrict__ x,
                                               const float* __restrict__ Wi,
                                               const float* __restrict__ bi,
                                               float* __restrict__ h, bf16* __restrict__ hbf,
                                               bf16* __restrict__ hT) {
  __shared__ float xs[4][IN_DIM];
  __shared__ float red[8];
  int r0 = blockIdx.x * 4;
  int tid = threadIdx.x;
  for (int idx = tid; idx < 4 * IN_DIM; idx += 256) {
    int rr = idx / IN_DIM, k = idx % IN_DIM;
    xs[rr][k] = x[(size_t)(r0 + rr) * IN_DIM + k];
  }
  __syncthreads();
  float acc[4][2] = {};
  for (int k = 0; k < IN_DIM; ++k) {
    float w0 = Wi[(size_t)k * 512 + tid];
    float w1 = Wi[(size_t)k * 512 + tid + 256];
#pragma unroll
    for (int rr = 0; rr < 4; ++rr) {
      acc[rr][0] += xs[rr][k] * w0;
      acc[rr][1] += xs[rr][k] * w1;
    }
  }
  float b0 = bi[tid], b1 = bi[tid + 256];
  for (int rr = 0; rr < 4; ++rr) {
    float v0 = acc[rr][0] + b0, v1 = acc[rr][1] + b1;
    float s = v0 + v1, s2 = v0 * v0 + v1 * v1;
    block_sum2(s, s2, red);
    float mean = s * (1.f / 512.f);
    float var = s2 * (1.f / 512.f) - mean * mean;
    float rs = rsqrtf(var + 1e-5f);
    float o0 = (v0 - mean) * rs, o1 = (v1 - mean) * rs;
    int r = r0 + rr;
    h[(size_t)r * 512 + tid] = o0;
    h[(size_t)r * 512 + tid + 256] = o1;
    hbf[(size_t)r * 512 + tid] = (bf16)o0;
    hbf[(size_t)r * 512 + tid + 256] = (bf16)o1;
    int b = r >> 10, t = r & (T_SEQ - 1);
    hT[((size_t)b * 512 + tid) * T_SEQ + t] = (bf16)o0;
    hT[((size_t)b * 512 + tid + 256) * T_SEQ + t] = (bf16)o1;
  }
}

// ---------- in-place LN on bf16 rows of 512 ----------
__global__ __launch_bounds__(256) void ln_rows(bf16* __restrict__ io) {
  __shared__ float red[8];
  size_t r = blockIdx.x;
  int tid = threadIdx.x;
  float v0 = (float)io[r * 512 + tid], v1 = (float)io[r * 512 + tid + 256];
  float s = v0 + v1, s2 = v0 * v0 + v1 * v1;
  block_sum2(s, s2, red);
  float mean = s * (1.f / 512.f);
  float var = s2 * (1.f / 512.f) - mean * mean;
  float rs = rsqrtf(var + 1e-5f);
  io[r * 512 + tid] = (bf16)((v0 - mean) * rs);
  io[r * 512 + tid + 256] = (bf16)((v1 - mean) * rs);
}

// ---------- h = LN(h_res + LN(z)) ----------
__global__ __launch_bounds__(256) void ln_double(const float* __restrict__ zin,
                                                 float* __restrict__ h, bf16* __restrict__ hbf,
                                                 bf16* __restrict__ hT) {
  __shared__ float red[8];
  size_t r = blockIdx.x;
  int tid = threadIdx.x;
  float z0 = zin[r * 512 + tid], z1 = zin[r * 512 + tid + 256];
  float s = z0 + z1, s2 = z0 * z0 + z1 * z1;
  block_sum2(s, s2, red);
  float m1 = s * (1.f / 512.f);
  float v1_ = s2 * (1.f / 512.f) - m1 * m1;
  float rs1 = rsqrtf(v1_ + 1e-5f);
  float a0 = (z0 - m1) * rs1 + h[r * 512 + tid];
  float a1 = (z1 - m1) * rs1 + h[r * 512 + tid + 256];
  s = a0 + a1;
  s2 = a0 * a0 + a1 * a1;
  block_sum2(s, s2, red);
  float m2 = s * (1.f / 512.f);
  float v2_ = s2 * (1.f / 512.f) - m2 * m2;
  float rs2 = rsqrtf(v2_ + 1e-5f);
  float o0 = (a0 - m2) * rs2, o1 = (a1 - m2) * rs2;
  h[r * 512 + tid] = o0;
  h[r * 512 + tid + 256] = o1;
  hbf[r * 512 + tid] = (bf16)o0;
  hbf[r * 512 + tid + 256] = (bf16)o1;
  int b = (int)(r >> 10), t = (int)(r & (T_SEQ - 1));
  hT[((size_t)b * 512 + tid) * T_SEQ + t] = (bf16)o0;
  hT[((size_t)b * 512 + tid + 256) * T_SEQ + t] = (bf16)o1;
}

// ---------- out = h @ Wo + bo ----------
__global__ __launch_bounds__(192) void out_proj(const float* __restrict__ h,
                                                const float* __restrict__ Wo,
                                                const float* __restrict__ bo,
                                                float* __restrict__ out) {
  __shared__ float hs[4][512];
  int r0 = blockIdx.x * 4, tid = threadIdx.x;
  for (int idx = tid; idx < 4 * 512; idx += 192) hs[idx >> 9][idx & 511] = h[(size_t)r0 * 512 + idx];
  __syncthreads();
  if (tid < OUT_DIM) {
    float bb = bo[tid];
    float acc[4] = {bb, bb, bb, bb};
    for (int k = 0; k < 512; ++k) {
      float w = Wo[(size_t)k * OUT_DIM + tid];
#pragma unroll
      for (int rr = 0; rr < 4; ++rr) acc[rr] += hs[rr][k] * w;
    }
#pragma unroll
    for (int rr = 0; rr < 4; ++rr) out[(size_t)(r0 + rr) * OUT_DIM + tid] = acc[rr];
  }
}

// ---------- 128x128 bf16 MFMA GEMM, C = A @ Bt^T ----------
// BK=64, double-buffered LDS, counted-vmcnt pipeline (T4), XOR-swizzled LDS (T2,
// via pre-swizzled global source per rule #21), 1-D grid with z=id&7 XCD pin (T1).
// MODE 0: hsp = relu(hbf_b @ encT^T)        z = head
// MODE 1: S   = causal_mask(qr @ qr^T)      z = head, compact lower-triangle
// MODE 2: ykv = bf16(S @ hT_b^T)            z = head, K bounded causally
// MODE 3: xy  = relu(ykv @ encvT^T) * hsp   z = head, token-major output
// MODE 4: z  += xy @ decT^T                 z = split-K chunk (atomicAdd)
template <int MODE, int GX>
__global__ __launch_bounds__(256, 2) void gemm_bt(const bf16* __restrict__ Abase,
                                                  const bf16* __restrict__ Bbase,
                                                  const bf16* __restrict__ aux,
                                                  float* __restrict__ fout,
                                                  bf16* __restrict__ bout) {
  const int id = blockIdx.x;
  const int bz = id & 7;      // XCD pin: all blocks of one z share an XCD
  const int r_ = id >> 3;
  int bi, bj;
  if constexpr (MODE == 1) {
    int l = r_;  // compact lower-triangle mapping: l -> (bi,bj), bj<=bi
    float f = sqrtf(8.0f * (float)l + 1.0f);
    bi = (int)((f - 1.0f) * 0.5f);
    while ((bi + 1) * (bi + 2) / 2 <= l) ++bi;
    while (bi * (bi + 1) / 2 > l) --bi;
    bj = l - bi * (bi + 1) / 2;
  } else {
    bi = r_ % GX;
    bj = r_ / GX;
  }

  const bf16* A;
  const bf16* Bt;
  int lda, ldb, kend;
  if constexpr (MODE == 0) {
    A = Abase; lda = 512;
    Bt = Bbase + (size_t)bz * N_INT * 512; ldb = 512;
    kend = 512;
  } else if constexpr (MODE == 1) {
    A = Abase + (size_t)bz * T_SEQ * N_INT; lda = N_INT;
    Bt = A; ldb = N_INT;
    kend = N_INT;
  } else if constexpr (MODE == 2) {
    A = Abase + (size_t)bz * T_SEQ * T_SEQ; lda = T_SEQ;
    Bt = Bbase; ldb = T_SEQ;
    kend = (bi + 1) * 128;  // causal bound
  } else if constexpr (MODE == 3) {
    A = Abase + (size_t)bz * T_SEQ * 512; lda = 512;
    Bt = Bbase + (size_t)bz * N_INT * 512; ldb = 512;
    kend = 512;
  } else {
    A = Abase + (size_t)bz * 2048; lda = 16384;
    Bt = Bbase + (size_t)bz * 2048; ldb = 16384;
    kend = 2048;
  }

  const int tid = threadIdx.x;
  // staging: 4 passes/matrix, 32 rows/pass, 8 threads/row, 16B each.
  // source col-slot XOR'ed by row&7 so that LINEAR LDS + swizzled read = conflict-free.
  const int trow = tid >> 3, tq = tid & 7;
  const int sq = tq ^ (trow & 7);
  const bf16* ags = A + (size_t)(bi * 128 + trow) * lda + sq * 8;
  const bf16* bgs = Bt + (size_t)(bj * 128 + trow) * ldb + sq * 8;

  __shared__ __align__(16) bf16 As[2][128 * 64];
  __shared__ __align__(16) bf16 Bs[2][128 * 64];
  const int so = tid * 8;  // linear dest: row*64 + slot*8 == tid*8  (+ pass*2048)

  const int lane = tid & 63, wid = tid >> 6;
  const int wr = wid >> 1, wc = wid & 1;
  const int fr = lane & 15, fg = lane >> 4;
  const int axor = fr & 7;

  f32x4 acc[4][4] = {};

  auto stage = [&](int buf, int kk) {
#pragma unroll
    for (int p = 0; p < 4; ++p) {
      gld16(ags + (size_t)(p * 32) * lda + kk, &As[buf][p * 2048 + so]);
      gld16(bgs + (size_t)(p * 32) * ldb + kk, &Bs[buf][p * 2048 + so]);
    }
  };

  const int nt = kend >> 6;
  stage(0, 0);

  for (int t = 0; t < nt; ++t) {
    const int cur = t & 1;
    if (t + 1 < nt) {
      stage(cur ^ 1, (t + 1) << 6);
      asm volatile("s_waitcnt vmcnt(8)" ::: "memory");  // tile t resident; t+1 in flight
    } else {
      asm volatile("s_waitcnt vmcnt(0)" ::: "memory");
    }
    __builtin_amdgcn_sched_barrier(0);
    __builtin_amdgcn_s_barrier();  // all waves' LDS writes for tile t visible
    __builtin_amdgcn_sched_barrier(0);

    __builtin_amdgcn_s_setprio(1);
#pragma unroll
    for (int s = 0; s < 2; ++s) {
      bf16x8 af[4], bfv[4];
#pragma unroll
      for (int m = 0; m < 4; ++m)
        af[m] = *(const bf16x8*)(&As[cur][(wr * 64 + m * 16 + fr) * 64 + (((s * 4 + fg) ^ axor) * 8)]);
#pragma unroll
      for (int n = 0; n < 4; ++n)
        bfv[n] = *(const bf16x8*)(&Bs[cur][(wc * 64 + n * 16 + fr) * 64 + (((s * 4 + fg) ^ axor) * 8)]);
#pragma unroll
      for (int m = 0; m < 4; ++m)
#pragma unroll
        for (int n = 0; n < 4; ++n)
          acc[m][n] = __builtin_amdgcn_mfma_f32_16x16x32_bf16(af[m], bfv[n], acc[m][n], 0, 0, 0);
    }
    __builtin_amdgcn_s_setprio(0);

    // WAR fence: all waves done reading buf[cur] before iter t+1 stages into it
    asm volatile("s_waitcnt lgkmcnt(0)" ::: "memory");
    __builtin_amdgcn_sched_barrier(0);
    __builtin_amdgcn_s_barrier();
    __builtin_amdgcn_sched_barrier(0);
  }

#pragma unroll
  for (int m = 0; m < 4; ++m) {
#pragma unroll
    for (int n = 0; n < 4; ++n) {
#pragma unroll
      for (int j = 0; j < 4; ++j) {
        int r = bi * 128 + wr * 64 + m * 16 + fg * 4 + j;
        int c = bj * 128 + wc * 64 + n * 16 + fr;
        float v = acc[m][n][j];
        if constexpr (MODE == 0) {
          v = fmaxf(v, 0.f);
          bout[((size_t)bz * T_SEQ + r) * N_INT + c] = (bf16)v;
        } else if constexpr (MODE == 1) {
          bout[(size_t)bz * T_SEQ * T_SEQ + (size_t)r * T_SEQ + c] = (bf16)(c < r ? v : 0.f);
        } else if constexpr (MODE == 2) {
          bout[((size_t)bz * T_SEQ + r) * 512 + c] = (bf16)v;
        } else if constexpr (MODE == 3) {
          v = fmaxf(v, 0.f);
          float g = (float)aux[((size_t)bz * T_SEQ + r) * N_INT + c];
          bout[(size_t)r * 16384 + (size_t)bz * N_INT + c] = (bf16)(v * g);
        } else {
          atomicAdd(fout + (size_t)r * 512 + c, v);
        }
      }
    }
  }
}

// ---------- launch ----------
extern "C" void kernel_launch(void* const* d_in, const int* in_sizes, int n_in,
                              void* d_out, int out_size, void* d_ws, size_t ws_size,
                              hipStream_t stream) {
  const float* x = (const float*)d_in[0];
  const float* Wi = (const float*)d_in[1];
  const float* bi = (const float*)d_in[2];
  const float* enc = (const float*)d_in[3];
  const float* encv = (const float*)d_in[4];
  const float* dec = (const float*)d_in[5];
  const float* Wo = (const float*)d_in[6];
  const float* bo = (const float*)d_in[7];
  float* out = (float*)d_out;

  const size_t NEED = 163577856;
  if (ws_size < NEED) return;

  char* w = (char*)d_ws;
  auto alloc = [&](size_t bytes) {
    char* p = w;
    w += (bytes + 255) & ~(size_t)255;
    return p;
  };
  bf16* encT = (bf16*)alloc((size_t)NHEADS * N_INT * 512 * 2);
  bf16* encvT = (bf16*)alloc((size_t)NHEADS * N_INT * 512 * 2);
  bf16* decT = (bf16*)alloc((size_t)512 * 16384 * 2);
  float* cost = (float*)alloc((size_t)T_SEQ * 1024 * 4);
  float* sint = (float*)alloc((size_t)T_SEQ * 1024 * 4);
  float* h = (float*)alloc((size_t)2048 * 512 * 4);
  bf16* hbf = (bf16*)alloc((size_t)2048 * 512 * 2);
  bf16* hT = (bf16*)alloc((size_t)2048 * 512 * 2);
  bf16* hsp = (bf16*)alloc((size_t)NHEADS * T_SEQ * N_INT * 2);
  bf16* qr = (bf16*)alloc((size_t)NHEADS * T_SEQ * N_INT * 2);
  bf16* S = (bf16*)alloc((size_t)NHEADS * T_SEQ * T_SEQ * 2);
  bf16* ykv = (bf16*)alloc((size_t)NHEADS * T_SEQ * 512 * 2);
  float* zbuf = (float*)alloc((size_t)2048 * 512 * 4);

  transpose_cvt<<<dim3(64, 16, 8), dim3(32, 8), 0, stream>>>(enc, encT, 512, N_INT);
  transpose_cvt<<<dim3(64, 16, 8), dim3(32, 8), 0, stream>>>(encv, encvT, 512, N_INT);
  transpose_cvt<<<dim3(16, 512, 1), dim3(32, 8), 0, stream>>>(dec, decT, 16384, 512);
  rope_tables<<<1024, 256, 0, stream>>>(cost, sint);
  in_proj<<<512, 256, 0, stream>>>(x, Wi, bi, h, hbf, hT);

  for (int L = 0; L < 3; ++L) {
    hipMemsetAsync(zbuf, 0, (size_t)2048 * 512 * 4, stream);
    for (int b = 0; b < 2; ++b) {
      const bf16* hbf_b = hbf + (size_t)b * T_SEQ * 512;
      const bf16* hT_b = hT + (size_t)b * 512 * T_SEQ;
      float* zbuf_b = zbuf + (size_t)b * T_SEQ * 512;
      gemm_bt<0, 8><<<1024, 256, 0, stream>>>(hbf_b, encT, nullptr, nullptr, hsp);
      rope_apply<<<4096, 256, 0, stream>>>(hsp, cost, sint, qr);
      gemm_bt<1, 36><<<288, 256, 0, stream>>>(qr, nullptr, nullptr, nullptr, S);
      gemm_bt<2, 8><<<256, 256, 0, stream>>>(S, hT_b, nullptr, nullptr, ykv);
      ln_rows<<<8192, 256, 0, stream>>>(ykv);
      gemm_bt<3, 8><<<1024, 256, 0, stream>>>(ykv, encvT, hsp, nullptr, qr);
      gemm_bt<4, 8><<<256, 256, 0, stream>>>(qr, decT, nullptr, zbuf_b, nullptr);
    }
    ln_double<<<2048, 256, 0, stream>>>(zbuf, h, hbf, hT);
  }
  out_proj<<<512, 192, 0, stream>>>(h, Wo, bo, out);
}

// Round 5
// 1106.755 us; speedup vs baseline: 1.2362x; 1.0175x over previous
//
#include <hip/hip_runtime.h>

// ---------- types ----------
typedef __bf16 bf16;
typedef __attribute__((ext_vector_type(8))) __bf16 bf16x8;
typedef __attribute__((ext_vector_type(4))) float f32x4;

#define T_SEQ 1024
#define D_MODEL 512
#define N_INT 2048
#define NHEADS 8
#define IN_DIM 372
#define IN_PAD 384
#define OUT_DIM 186
#define OUT_PAD 256

__device__ inline void gld16(const bf16* g, bf16* l) {
  __builtin_amdgcn_global_load_lds((const __attribute__((address_space(1))) void*)g,
                                   (__attribute__((address_space(3))) void*)l, 16, 0, 0);
}

// block-wide sum of two values (256 threads)
__device__ inline void block_sum2(float& a, float& b, float* red) {
#pragma unroll
  for (int o = 32; o > 0; o >>= 1) {
    a += __shfl_down(a, o, 64);
    b += __shfl_down(b, o, 64);
  }
  __syncthreads();
  if ((threadIdx.x & 63) == 0) {
    int w = threadIdx.x >> 6;
    red[2 * w] = a;
    red[2 * w + 1] = b;
  }
  __syncthreads();
  a = red[0] + red[2] + red[4] + red[6];
  b = red[1] + red[3] + red[5] + red[7];
}

// ---------- transpose + fp32->bf16 convert:  out[c][r] = in[r][c], per z-matrix ----------
__global__ __launch_bounds__(256) void transpose_cvt(const float* __restrict__ in,
                                                     bf16* __restrict__ out,
                                                     int rows, int cols) {
  __shared__ float tile[32][33];
  size_t zoff = (size_t)blockIdx.z * rows * cols;
  in += zoff;
  out += zoff;
  int c0 = blockIdx.x * 32, r0 = blockIdx.y * 32;
#pragma unroll
  for (int i = threadIdx.y; i < 32; i += 8)
    tile[i][threadIdx.x] = in[(size_t)(r0 + i) * cols + c0 + threadIdx.x];
  __syncthreads();
#pragma unroll
  for (int i = threadIdx.y; i < 32; i += 8)
    out[(size_t)(c0 + i) * rows + r0 + threadIdx.x] = (bf16)tile[threadIdx.x][i];
}

// ---------- zero-padded transpose + cvt: out[c][r0..] = in[r][c] (r<R, c<C else 0) ----------
__global__ __launch_bounds__(256) void pad_trans(const float* __restrict__ in,
                                                 bf16* __restrict__ out,
                                                 int R, int C, int outLd) {
  __shared__ float tile[32][33];
  int c0 = blockIdx.x * 32, r0 = blockIdx.y * 32;
#pragma unroll
  for (int i = threadIdx.y; i < 32; i += 8) {
    int r = r0 + i, c = c0 + threadIdx.x;
    tile[i][threadIdx.x] = (r < R && c < C) ? in[(size_t)r * C + c] : 0.f;
  }
  __syncthreads();
#pragma unroll
  for (int i = threadIdx.y; i < 32; i += 8)
    out[(size_t)(c0 + i) * outLd + r0 + threadIdx.x] = (bf16)tile[threadIdx.x][i];
}

// ---------- x fp32 [2048][372] -> xbf bf16 [2048][384] zero-padded ----------
__global__ __launch_bounds__(256) void cvt_pad_x(const float* __restrict__ x,
                                                 bf16* __restrict__ xbf) {
  size_t r = blockIdx.x;
  for (int c = threadIdx.x; c < IN_PAD; c += 256)
    xbf[r * IN_PAD + c] = (c < IN_DIM) ? (bf16)x[r * IN_DIM + c] : (bf16)0.f;
}

// ---------- RoPE tables ----------
__global__ __launch_bounds__(256) void rope_tables(float* __restrict__ ct, float* __restrict__ st) {
  int t = blockIdx.x;
  for (int i = threadIdx.x; i < 1024; i += 256) {
    float ph = (float)t * exp2f(-16.0f * (float)i * (1.0f / 1024.0f));
    ct[(size_t)t * 1024 + i] = cosf(ph);
    st[(size_t)t * 1024 + i] = sinf(ph);
  }
}

// ---------- RoPE apply (per batch) ----------
__global__ __launch_bounds__(256) void rope_apply(const bf16* __restrict__ hsp,
                                                  const float* __restrict__ ct,
                                                  const float* __restrict__ st,
                                                  bf16* __restrict__ qr) {
  size_t row = (size_t)blockIdx.x * 2 + (threadIdx.x >> 7);
  int i = threadIdx.x & 127;
  int t = (int)(row & (T_SEQ - 1));
  const bf16* src = hsp + row * N_INT;
  bf16* dst = qr + row * N_INT;
  int n1 = i * 8;
  bf16x8 x1 = *(const bf16x8*)(src + n1);
  bf16x8 x2 = *(const bf16x8*)(src + n1 + 1024);
  const float* cp = ct + (size_t)t * 1024 + n1;
  const float* sp = st + (size_t)t * 1024 + n1;
  bf16x8 o1, o2;
#pragma unroll
  for (int j = 0; j < 8; ++j) {
    float c = cp[j], s = sp[j];
    float a = (float)x1[j], b = (float)x2[j];
    o1[j] = (bf16)(a * c - b * s);
    o2[j] = (bf16)(b * c + a * s);
  }
  *(bf16x8*)(dst + n1) = o1;
  *(bf16x8*)(dst + n1 + 1024) = o2;
}

// ---------- ln0: h = LN(z); writes h fp32, hbf, hT ----------
__global__ __launch_bounds__(256) void ln0(const float* __restrict__ zin,
                                           float* __restrict__ h, bf16* __restrict__ hbf,
                                           bf16* __restrict__ hT) {
  __shared__ float red[8];
  size_t r = blockIdx.x;
  int tid = threadIdx.x;
  float v0 = zin[r * 512 + tid], v1 = zin[r * 512 + tid + 256];
  float s = v0 + v1, s2 = v0 * v0 + v1 * v1;
  block_sum2(s, s2, red);
  float mean = s * (1.f / 512.f);
  float var = s2 * (1.f / 512.f) - mean * mean;
  float rs = rsqrtf(var + 1e-5f);
  float o0 = (v0 - mean) * rs, o1 = (v1 - mean) * rs;
  h[r * 512 + tid] = o0;
  h[r * 512 + tid + 256] = o1;
  hbf[r * 512 + tid] = (bf16)o0;
  hbf[r * 512 + tid + 256] = (bf16)o1;
  int b = (int)(r >> 10), t = (int)(r & (T_SEQ - 1));
  hT[((size_t)b * 512 + tid) * T_SEQ + t] = (bf16)o0;
  hT[((size_t)b * 512 + tid + 256) * T_SEQ + t] = (bf16)o1;
}

// ---------- in-place LN on bf16 rows of 512 ----------
__global__ __launch_bounds__(256) void ln_rows(bf16* __restrict__ io) {
  __shared__ float red[8];
  size_t r = blockIdx.x;
  int tid = threadIdx.x;
  float v0 = (float)io[r * 512 + tid], v1 = (float)io[r * 512 + tid + 256];
  float s = v0 + v1, s2 = v0 * v0 + v1 * v1;
  block_sum2(s, s2, red);
  float mean = s * (1.f / 512.f);
  float var = s2 * (1.f / 512.f) - mean * mean;
  float rs = rsqrtf(var + 1e-5f);
  io[r * 512 + tid] = (bf16)((v0 - mean) * rs);
  io[r * 512 + tid + 256] = (bf16)((v1 - mean) * rs);
}

// ---------- h = LN(h_res + LN(z)) ----------
__global__ __launch_bounds__(256) void ln_double(const float* __restrict__ zin,
                                                 float* __restrict__ h, bf16* __restrict__ hbf,
                                                 bf16* __restrict__ hT) {
  __shared__ float red[8];
  size_t r = blockIdx.x;
  int tid = threadIdx.x;
  float z0 = zin[r * 512 + tid], z1 = zin[r * 512 + tid + 256];
  float s = z0 + z1, s2 = z0 * z0 + z1 * z1;
  block_sum2(s, s2, red);
  float m1 = s * (1.f / 512.f);
  float v1_ = s2 * (1.f / 512.f) - m1 * m1;
  float rs1 = rsqrtf(v1_ + 1e-5f);
  float a0 = (z0 - m1) * rs1 + h[r * 512 + tid];
  float a1 = (z1 - m1) * rs1 + h[r * 512 + tid + 256];
  s = a0 + a1;
  s2 = a0 * a0 + a1 * a1;
  block_sum2(s, s2, red);
  float m2 = s * (1.f / 512.f);
  float v2_ = s2 * (1.f / 512.f) - m2 * m2;
  float rs2 = rsqrtf(v2_ + 1e-5f);
  float o0 = (a0 - m2) * rs2, o1 = (a1 - m2) * rs2;
  h[r * 512 + tid] = o0;
  h[r * 512 + tid + 256] = o1;
  hbf[r * 512 + tid] = (bf16)o0;
  hbf[r * 512 + tid + 256] = (bf16)o1;
  int b = (int)(r >> 10), t = (int)(r & (T_SEQ - 1));
  hT[((size_t)b * 512 + tid) * T_SEQ + t] = (bf16)o0;
  hT[((size_t)b * 512 + tid + 256) * T_SEQ + t] = (bf16)o1;
}

// ---------- 128x128 bf16 MFMA GEMM, C = A @ Bt^T ----------
// BK=64, double-buffered LDS, counted-vmcnt pipeline (T4), XOR-swizzled LDS (T2,
// via pre-swizzled global source per rule #21), 1-D grid with z=id&7 XCD pin (T1).
// MODE 0: hsp = relu(hbf_b @ encT^T)        z = head
// MODE 1: S   = causal_mask(qr @ qr^T)      z = head, compact lower-triangle
// MODE 2: ykv = bf16(S @ hT_b^T)            z = head, K bounded causally
// MODE 3: xy  = relu(ykv @ encvT^T) * hsp   z = head, token-major output
// MODE 4: z  += xy @ decT^T                 z = split-K chunk (atomicAdd)
// MODE 5: zbuf = xbf @ WiT^T + bi           (input projection, z unused)
// MODE 6: out  = hbf @ WoT^T + bo           (output projection, masked c<186)
template <int MODE, int GX>
__global__ __launch_bounds__(256, 2) void gemm_bt(const bf16* __restrict__ Abase,
                                                  const bf16* __restrict__ Bbase,
                                                  const bf16* __restrict__ aux,
                                                  const float* __restrict__ fbias,
                                                  float* __restrict__ fout,
                                                  bf16* __restrict__ bout) {
  const int id = blockIdx.x;
  int bz, r_;
  if constexpr (MODE >= 5) {
    bz = 0;
    r_ = id;
  } else {
    bz = id & 7;  // XCD pin: all blocks of one z share an XCD
    r_ = id >> 3;
  }
  int bi, bj;
  if constexpr (MODE == 1) {
    int l = r_;  // compact lower-triangle mapping: l -> (bi,bj), bj<=bi
    float f = sqrtf(8.0f * (float)l + 1.0f);
    bi = (int)((f - 1.0f) * 0.5f);
    while ((bi + 1) * (bi + 2) / 2 <= l) ++bi;
    while (bi * (bi + 1) / 2 > l) --bi;
    bj = l - bi * (bi + 1) / 2;
  } else {
    bi = r_ % GX;
    bj = r_ / GX;
  }

  const bf16* A;
  const bf16* Bt;
  int lda, ldb, kend;
  if constexpr (MODE == 0) {
    A = Abase; lda = 512;
    Bt = Bbase + (size_t)bz * N_INT * 512; ldb = 512;
    kend = 512;
  } else if constexpr (MODE == 1) {
    A = Abase + (size_t)bz * T_SEQ * N_INT; lda = N_INT;
    Bt = A; ldb = N_INT;
    kend = N_INT;
  } else if constexpr (MODE == 2) {
    A = Abase + (size_t)bz * T_SEQ * T_SEQ; lda = T_SEQ;
    Bt = Bbase; ldb = T_SEQ;
    kend = (bi + 1) * 128;  // causal bound
  } else if constexpr (MODE == 3) {
    A = Abase + (size_t)bz * T_SEQ * 512; lda = 512;
    Bt = Bbase + (size_t)bz * N_INT * 512; ldb = 512;
    kend = 512;
  } else if constexpr (MODE == 4) {
    A = Abase + (size_t)bz * 2048; lda = 16384;
    Bt = Bbase + (size_t)bz * 2048; ldb = 16384;
    kend = 2048;
  } else if constexpr (MODE == 5) {
    A = Abase; lda = IN_PAD;
    Bt = Bbase; ldb = IN_PAD;
    kend = IN_PAD;
  } else {
    A = Abase; lda = 512;
    Bt = Bbase; ldb = 512;
    kend = 512;
  }

  const int tid = threadIdx.x;
  // staging: 4 passes/matrix, 32 rows/pass, 8 threads/row, 16B each.
  // source col-slot XOR'ed by row&7 so that LINEAR LDS + swizzled read = conflict-free.
  const int trow = tid >> 3, tq = tid & 7;
  const int sq = tq ^ (trow & 7);
  const bf16* ags = A + (size_t)(bi * 128 + trow) * lda + sq * 8;
  const bf16* bgs = Bt + (size_t)(bj * 128 + trow) * ldb + sq * 8;

  __shared__ __align__(16) bf16 As[2][128 * 64];
  __shared__ __align__(16) bf16 Bs[2][128 * 64];
  const int so = tid * 8;  // linear dest: row*64 + slot*8 == tid*8  (+ pass*2048)

  const int lane = tid & 63, wid = tid >> 6;
  const int wr = wid >> 1, wc = wid & 1;
  const int fr = lane & 15, fg = lane >> 4;
  const int axor = fr & 7;

  f32x4 acc[4][4] = {};

  auto stage = [&](int buf, int kk) {
#pragma unroll
    for (int p = 0; p < 4; ++p) {
      gld16(ags + (size_t)(p * 32) * lda + kk, &As[buf][p * 2048 + so]);
      gld16(bgs + (size_t)(p * 32) * ldb + kk, &Bs[buf][p * 2048 + so]);
    }
  };

  const int nt = kend >> 6;
  stage(0, 0);

  for (int t = 0; t < nt; ++t) {
    const int cur = t & 1;
    if (t + 1 < nt) {
      stage(cur ^ 1, (t + 1) << 6);
      asm volatile("s_waitcnt vmcnt(8)" ::: "memory");  // tile t resident; t+1 in flight
    } else {
      asm volatile("s_waitcnt vmcnt(0)" ::: "memory");
    }
    __builtin_amdgcn_sched_barrier(0);
    __builtin_amdgcn_s_barrier();  // all waves' LDS writes for tile t visible
    __builtin_amdgcn_sched_barrier(0);

    __builtin_amdgcn_s_setprio(1);
#pragma unroll
    for (int s = 0; s < 2; ++s) {
      bf16x8 af[4], bfv[4];
#pragma unroll
      for (int m = 0; m < 4; ++m)
        af[m] = *(const bf16x8*)(&As[cur][(wr * 64 + m * 16 + fr) * 64 + (((s * 4 + fg) ^ axor) * 8)]);
#pragma unroll
      for (int n = 0; n < 4; ++n)
        bfv[n] = *(const bf16x8*)(&Bs[cur][(wc * 64 + n * 16 + fr) * 64 + (((s * 4 + fg) ^ axor) * 8)]);
#pragma unroll
      for (int m = 0; m < 4; ++m)
#pragma unroll
        for (int n = 0; n < 4; ++n)
          acc[m][n] = __builtin_amdgcn_mfma_f32_16x16x32_bf16(af[m], bfv[n], acc[m][n], 0, 0, 0);
    }
    __builtin_amdgcn_s_setprio(0);

    // WAR fence: all waves done reading buf[cur] before iter t+1 stages into it
    asm volatile("s_waitcnt lgkmcnt(0)" ::: "memory");
    __builtin_amdgcn_sched_barrier(0);
    __builtin_amdgcn_s_barrier();
    __builtin_amdgcn_sched_barrier(0);
  }

#pragma unroll
  for (int m = 0; m < 4; ++m) {
#pragma unroll
    for (int n = 0; n < 4; ++n) {
#pragma unroll
      for (int j = 0; j < 4; ++j) {
        int r = bi * 128 + wr * 64 + m * 16 + fg * 4 + j;
        int c = bj * 128 + wc * 64 + n * 16 + fr;
        float v = acc[m][n][j];
        if constexpr (MODE == 0) {
          v = fmaxf(v, 0.f);
          bout[((size_t)bz * T_SEQ + r) * N_INT + c] = (bf16)v;
        } else if constexpr (MODE == 1) {
          bout[(size_t)bz * T_SEQ * T_SEQ + (size_t)r * T_SEQ + c] = (bf16)(c < r ? v : 0.f);
        } else if constexpr (MODE == 2) {
          bout[((size_t)bz * T_SEQ + r) * 512 + c] = (bf16)v;
        } else if constexpr (MODE == 3) {
          v = fmaxf(v, 0.f);
          float g = (float)aux[((size_t)bz * T_SEQ + r) * N_INT + c];
          bout[(size_t)r * 16384 + (size_t)bz * N_INT + c] = (bf16)(v * g);
        } else if constexpr (MODE == 4) {
          atomicAdd(fout + (size_t)r * 512 + c, v);
        } else if constexpr (MODE == 5) {
          fout[(size_t)r * 512 + c] = v + fbias[c];
        } else {
          if (c < OUT_DIM) fout[(size_t)r * OUT_DIM + c] = v + fbias[c];
        }
      }
    }
  }
}

// ---------- launch ----------
extern "C" void kernel_launch(void* const* d_in, const int* in_sizes, int n_in,
                              void* d_out, int out_size, void* d_ws, size_t ws_size,
                              hipStream_t stream) {
  const float* x = (const float*)d_in[0];
  const float* Wi = (const float*)d_in[1];
  const float* bi = (const float*)d_in[2];
  const float* enc = (const float*)d_in[3];
  const float* encv = (const float*)d_in[4];
  const float* dec = (const float*)d_in[5];
  const float* Wo = (const float*)d_in[6];
  const float* bo = (const float*)d_in[7];
  float* out = (float*)d_out;

  const size_t NEED = 163840000;
  if (ws_size < NEED) return;

  char* w = (char*)d_ws;
  auto alloc = [&](size_t bytes) {
    char* p = w;
    w += (bytes + 255) & ~(size_t)255;
    return p;
  };
  bf16* encT = (bf16*)alloc((size_t)NHEADS * N_INT * 512 * 2);
  bf16* encvT = (bf16*)alloc((size_t)NHEADS * N_INT * 512 * 2);
  bf16* decT = (bf16*)alloc((size_t)512 * 16384 * 2);
  float* cost = (float*)alloc((size_t)T_SEQ * 1024 * 4);
  float* sint = (float*)alloc((size_t)T_SEQ * 1024 * 4);
  float* h = (float*)alloc((size_t)2048 * 512 * 4);
  bf16* hbf = (bf16*)alloc((size_t)2048 * 512 * 2);
  bf16* hT = (bf16*)alloc((size_t)2048 * 512 * 2);
  bf16* hsp = (bf16*)alloc((size_t)NHEADS * T_SEQ * N_INT * 2);
  bf16* qr = (bf16*)alloc((size_t)NHEADS * T_SEQ * N_INT * 2);
  bf16* S = (bf16*)alloc((size_t)NHEADS * T_SEQ * T_SEQ * 2);
  bf16* ykv = (bf16*)alloc((size_t)NHEADS * T_SEQ * 512 * 2);
  float* zbuf = (float*)alloc((size_t)2048 * 512 * 4);
  bf16* WoT = (bf16*)alloc((size_t)OUT_PAD * 512 * 2);
  // xbf and WiT alias the S buffer (S is dead until the first MODE-1 launch)
  bf16* xbf = S;                  // 2048*384*2 = 1.5 MB
  bf16* WiT = S + 1048576;        // at byte offset 2 MB; 512*384*2 = 384 KB

  // --- prologue: weight prep + input projection (MFMA) ---
  transpose_cvt<<<dim3(64, 16, 8), dim3(32, 8), 0, stream>>>(enc, encT, 512, N_INT);
  transpose_cvt<<<dim3(64, 16, 8), dim3(32, 8), 0, stream>>>(encv, encvT, 512, N_INT);
  transpose_cvt<<<dim3(16, 512, 1), dim3(32, 8), 0, stream>>>(dec, decT, 16384, 512);
  pad_trans<<<dim3(16, 12), dim3(32, 8), 0, stream>>>(Wi, WiT, IN_DIM, 512, IN_PAD);
  pad_trans<<<dim3(8, 16), dim3(32, 8), 0, stream>>>(Wo, WoT, 512, OUT_DIM, 512);
  cvt_pad_x<<<2048, 256, 0, stream>>>(x, xbf);
  rope_tables<<<1024, 256, 0, stream>>>(cost, sint);
  gemm_bt<5, 16><<<64, 256, 0, stream>>>(xbf, WiT, nullptr, bi, zbuf, nullptr);
  ln0<<<2048, 256, 0, stream>>>(zbuf, h, hbf, hT);

  for (int L = 0; L < 3; ++L) {
    hipMemsetAsync(zbuf, 0, (size_t)2048 * 512 * 4, stream);
    for (int b = 0; b < 2; ++b) {
      const bf16* hbf_b = hbf + (size_t)b * T_SEQ * 512;
      const bf16* hT_b = hT + (size_t)b * 512 * T_SEQ;
      float* zbuf_b = zbuf + (size_t)b * T_SEQ * 512;
      gemm_bt<0, 8><<<1024, 256, 0, stream>>>(hbf_b, encT, nullptr, nullptr, nullptr, hsp);
      rope_apply<<<4096, 256, 0, stream>>>(hsp, cost, sint, qr);
      gemm_bt<1, 36><<<288, 256, 0, stream>>>(qr, nullptr, nullptr, nullptr, nullptr, S);
      gemm_bt<2, 8><<<256, 256, 0, stream>>>(S, hT_b, nullptr, nullptr, nullptr, ykv);
      ln_rows<<<8192, 256, 0, stream>>>(ykv);
      gemm_bt<3, 8><<<1024, 256, 0, stream>>>(ykv, encvT, hsp, nullptr, nullptr, qr);
      gemm_bt<4, 8><<<256, 256, 0, stream>>>(qr, decT, nullptr, nullptr, zbuf_b, nullptr);
    }
    ln_double<<<2048, 256, 0, stream>>>(zbuf, h, hbf, hT);
  }
  gemm_bt<6, 16><<<32, 256, 0, stream>>>(hbf, WoT, nullptr, bo, out, nullptr);
}

// Round 6
// 1025.087 us; speedup vs baseline: 1.3347x; 1.0797x over previous
//
#include <hip/hip_runtime.h>

// ---------- types ----------
typedef __bf16 bf16;
typedef __attribute__((ext_vector_type(8))) __bf16 bf16x8;
typedef __attribute__((ext_vector_type(4))) float f32x4;

#define T_SEQ 1024
#define D_MODEL 512
#define N_INT 2048
#define NHEADS 8
#define IN_DIM 372
#define IN_PAD 384
#define OUT_DIM 186
#define OUT_PAD 256

__device__ inline void gld16(const bf16* g, bf16* l) {
  __builtin_amdgcn_global_load_lds((const __attribute__((address_space(1))) void*)g,
                                   (__attribute__((address_space(3))) void*)l, 16, 0, 0);
}

// block-wide sum of two values (256 threads)
__device__ inline void block_sum2(float& a, float& b, float* red) {
#pragma unroll
  for (int o = 32; o > 0; o >>= 1) {
    a += __shfl_down(a, o, 64);
    b += __shfl_down(b, o, 64);
  }
  __syncthreads();
  if ((threadIdx.x & 63) == 0) {
    int w = threadIdx.x >> 6;
    red[2 * w] = a;
    red[2 * w + 1] = b;
  }
  __syncthreads();
  a = red[0] + red[2] + red[4] + red[6];
  b = red[1] + red[3] + red[5] + red[7];
}

// ---------- transpose + fp32->bf16 convert ----------
__global__ __launch_bounds__(256) void transpose_cvt(const float* __restrict__ in,
                                                     bf16* __restrict__ out,
                                                     int rows, int cols) {
  __shared__ float tile[32][33];
  size_t zoff = (size_t)blockIdx.z * rows * cols;
  in += zoff;
  out += zoff;
  int c0 = blockIdx.x * 32, r0 = blockIdx.y * 32;
#pragma unroll
  for (int i = threadIdx.y; i < 32; i += 8)
    tile[i][threadIdx.x] = in[(size_t)(r0 + i) * cols + c0 + threadIdx.x];
  __syncthreads();
#pragma unroll
  for (int i = threadIdx.y; i < 32; i += 8)
    out[(size_t)(c0 + i) * rows + r0 + threadIdx.x] = (bf16)tile[threadIdx.x][i];
}

// ---------- zero-padded transpose + cvt ----------
__global__ __launch_bounds__(256) void pad_trans(const float* __restrict__ in,
                                                 bf16* __restrict__ out,
                                                 int R, int C, int outLd) {
  __shared__ float tile[32][33];
  int c0 = blockIdx.x * 32, r0 = blockIdx.y * 32;
#pragma unroll
  for (int i = threadIdx.y; i < 32; i += 8) {
    int r = r0 + i, c = c0 + threadIdx.x;
    tile[i][threadIdx.x] = (r < R && c < C) ? in[(size_t)r * C + c] : 0.f;
  }
  __syncthreads();
#pragma unroll
  for (int i = threadIdx.y; i < 32; i += 8)
    out[(size_t)(c0 + i) * outLd + r0 + threadIdx.x] = (bf16)tile[threadIdx.x][i];
}

// ---------- x fp32 [2048][372] -> xbf bf16 [2048][384] zero-padded ----------
__global__ __launch_bounds__(256) void cvt_pad_x(const float* __restrict__ x,
                                                 bf16* __restrict__ xbf) {
  size_t r = blockIdx.x;
  for (int c = threadIdx.x; c < IN_PAD; c += 256)
    xbf[r * IN_PAD + c] = (c < IN_DIM) ? (bf16)x[r * IN_DIM + c] : (bf16)0.f;
}

// ---------- RoPE tables ----------
__global__ __launch_bounds__(256) void rope_tables(float* __restrict__ ct, float* __restrict__ st) {
  int t = blockIdx.x;
  for (int i = threadIdx.x; i < 1024; i += 256) {
    float ph = (float)t * exp2f(-16.0f * (float)i * (1.0f / 1024.0f));
    ct[(size_t)t * 1024 + i] = cosf(ph);
    st[(size_t)t * 1024 + i] = sinf(ph);
  }
}

// ---------- RoPE apply (per batch) ----------
__global__ __launch_bounds__(256) void rope_apply(const bf16* __restrict__ hsp,
                                                  const float* __restrict__ ct,
                                                  const float* __restrict__ st,
                                                  bf16* __restrict__ qr) {
  size_t row = (size_t)blockIdx.x * 2 + (threadIdx.x >> 7);
  int i = threadIdx.x & 127;
  int t = (int)(row & (T_SEQ - 1));
  const bf16* src = hsp + row * N_INT;
  bf16* dst = qr + row * N_INT;
  int n1 = i * 8;
  bf16x8 x1 = *(const bf16x8*)(src + n1);
  bf16x8 x2 = *(const bf16x8*)(src + n1 + 1024);
  const float* cp = ct + (size_t)t * 1024 + n1;
  const float* sp = st + (size_t)t * 1024 + n1;
  bf16x8 o1, o2;
#pragma unroll
  for (int j = 0; j < 8; ++j) {
    float c = cp[j], s = sp[j];
    float a = (float)x1[j], b = (float)x2[j];
    o1[j] = (bf16)(a * c - b * s);
    o2[j] = (bf16)(b * c + a * s);
  }
  *(bf16x8*)(dst + n1) = o1;
  *(bf16x8*)(dst + n1 + 1024) = o2;
}

// ---------- sum 16 bf16 split-K partials -> fp32 zbuf (per batch) ----------
__global__ __launch_bounds__(256) void psum16(const bf16* __restrict__ part,
                                              float* __restrict__ zb) {
  size_t r = blockIdx.x;  // 1024 rows
  for (int cc = threadIdx.x; cc < 512; cc += 256) {
    float s = 0.f;
#pragma unroll
    for (int k = 0; k < 16; ++k)
      s += (float)part[((size_t)k << 19) + r * 512 + cc];
    zb[r * 512 + cc] = s;
  }
}

// ---------- ln0: h = LN(z) ----------
__global__ __launch_bounds__(256) void ln0(const float* __restrict__ zin,
                                           float* __restrict__ h, bf16* __restrict__ hbf,
                                           bf16* __restrict__ hT) {
  __shared__ float red[8];
  size_t r = blockIdx.x;
  int tid = threadIdx.x;
  float v0 = zin[r * 512 + tid], v1 = zin[r * 512 + tid + 256];
  float s = v0 + v1, s2 = v0 * v0 + v1 * v1;
  block_sum2(s, s2, red);
  float mean = s * (1.f / 512.f);
  float var = s2 * (1.f / 512.f) - mean * mean;
  float rs = rsqrtf(var + 1e-5f);
  float o0 = (v0 - mean) * rs, o1 = (v1 - mean) * rs;
  h[r * 512 + tid] = o0;
  h[r * 512 + tid + 256] = o1;
  hbf[r * 512 + tid] = (bf16)o0;
  hbf[r * 512 + tid + 256] = (bf16)o1;
  int b = (int)(r >> 10), t = (int)(r & (T_SEQ - 1));
  hT[((size_t)b * 512 + tid) * T_SEQ + t] = (bf16)o0;
  hT[((size_t)b * 512 + tid + 256) * T_SEQ + t] = (bf16)o1;
}

// ---------- in-place LN on bf16 rows of 512 ----------
__global__ __launch_bounds__(256) void ln_rows(bf16* __restrict__ io) {
  __shared__ float red[8];
  size_t r = blockIdx.x;
  int tid = threadIdx.x;
  float v0 = (float)io[r * 512 + tid], v1 = (float)io[r * 512 + tid + 256];
  float s = v0 + v1, s2 = v0 * v0 + v1 * v1;
  block_sum2(s, s2, red);
  float mean = s * (1.f / 512.f);
  float var = s2 * (1.f / 512.f) - mean * mean;
  float rs = rsqrtf(var + 1e-5f);
  io[r * 512 + tid] = (bf16)((v0 - mean) * rs);
  io[r * 512 + tid + 256] = (bf16)((v1 - mean) * rs);
}

// ---------- h = LN(h_res + LN(z)) ----------
__global__ __launch_bounds__(256) void ln_double(const float* __restrict__ zin,
                                                 float* __restrict__ h, bf16* __restrict__ hbf,
                                                 bf16* __restrict__ hT) {
  __shared__ float red[8];
  size_t r = blockIdx.x;
  int tid = threadIdx.x;
  float z0 = zin[r * 512 + tid], z1 = zin[r * 512 + tid + 256];
  float s = z0 + z1, s2 = z0 * z0 + z1 * z1;
  block_sum2(s, s2, red);
  float m1 = s * (1.f / 512.f);
  float v1_ = s2 * (1.f / 512.f) - m1 * m1;
  float rs1 = rsqrtf(v1_ + 1e-5f);
  float a0 = (z0 - m1) * rs1 + h[r * 512 + tid];
  float a1 = (z1 - m1) * rs1 + h[r * 512 + tid + 256];
  s = a0 + a1;
  s2 = a0 * a0 + a1 * a1;
  block_sum2(s, s2, red);
  float m2 = s * (1.f / 512.f);
  float v2_ = s2 * (1.f / 512.f) - m2 * m2;
  float rs2 = rsqrtf(v2_ + 1e-5f);
  float o0 = (a0 - m2) * rs2, o1 = (a1 - m2) * rs2;
  h[r * 512 + tid] = o0;
  h[r * 512 + tid + 256] = o1;
  hbf[r * 512 + tid] = (bf16)o0;
  hbf[r * 512 + tid + 256] = (bf16)o1;
  int b = (int)(r >> 10), t = (int)(r & (T_SEQ - 1));
  hT[((size_t)b * 512 + tid) * T_SEQ + t] = (bf16)o0;
  hT[((size_t)b * 512 + tid + 256) * T_SEQ + t] = (bf16)o1;
}

// ---------- TILE x TILE bf16 MFMA GEMM body, C = A @ Bt^T ----------
// BK=64 dbuf LDS, counted-vmcnt pipeline (T4), XOR-swizzle (T2), XCD pin (T1).
// MODE 0: hsp = relu(hbf_b @ encT^T)         TILE=128, z=head
// MODE 1: S   = causal(qr @ qr^T)            TILE=64,  z=head, compact lower-tri
// MODE 2: ykv = bf16(S @ hT_b^T)             TILE=64,  z=head, K causal-bounded
// MODE 3: xy  = relu(ykv @ encvT^T) * hsp    TILE=128, z=head, token-major out
// MODE 4: part[chunk] = bf16(xy @ decT^T)    TILE=128, split-K-16, no atomics
// MODE 5: zbuf = xbf @ WiT^T + bi            TILE=128
// MODE 6: out  = hbf @ WoT^T + bo            TILE=128, masked c<186
template <int MODE, int GX, int TILE>
__device__ __forceinline__ void gemm_body(const bf16* __restrict__ Abase,
                                          const bf16* __restrict__ Bbase,
                                          const bf16* __restrict__ aux,
                                          const float* __restrict__ fbias,
                                          float* __restrict__ fout,
                                          bf16* __restrict__ bout) {
  const int id = blockIdx.x;
  int bz = 0, r_, chunk = 0;
  if constexpr (MODE >= 5) {
    r_ = id;
  } else if constexpr (MODE == 4) {
    r_ = id & 31;        // 8 bi x 4 bj
    chunk = id >> 5;     // 16 K-chunks
  } else {
    bz = id & 7;         // XCD pin: all blocks of one head share an XCD
    r_ = id >> 3;
  }
  int bi, bj;
  if constexpr (MODE == 1) {
    int l = r_;  // compact lower-triangle decode, l < 136
    float f = sqrtf(8.0f * (float)l + 1.0f);
    bi = (int)((f - 1.0f) * 0.5f);
    while ((bi + 1) * (bi + 2) / 2 <= l) ++bi;
    while (bi * (bi + 1) / 2 > l) --bi;
    bj = l - bi * (bi + 1) / 2;
  } else {
    bi = r_ % GX;
    bj = r_ / GX;
  }

  const bf16* A;
  const bf16* Bt;
  int lda, ldb, kend;
  if constexpr (MODE == 0) {
    A = Abase; lda = 512;
    Bt = Bbase + (size_t)bz * N_INT * 512; ldb = 512;
    kend = 512;
  } else if constexpr (MODE == 1) {
    A = Abase + (size_t)bz * T_SEQ * N_INT; lda = N_INT;
    Bt = A; ldb = N_INT;
    kend = N_INT;
  } else if constexpr (MODE == 2) {
    A = Abase + (size_t)bz * T_SEQ * T_SEQ; lda = T_SEQ;
    Bt = Bbase; ldb = T_SEQ;
    kend = (bi + 1) * TILE;  // causal bound
  } else if constexpr (MODE == 3) {
    A = Abase + (size_t)bz * T_SEQ * 512; lda = 512;
    Bt = Bbase + (size_t)bz * N_INT * 512; ldb = 512;
    kend = 512;
  } else if constexpr (MODE == 4) {
    A = Abase + (size_t)chunk * 1024; lda = 16384;
    Bt = Bbase + (size_t)chunk * 1024; ldb = 16384;
    kend = 1024;
  } else if constexpr (MODE == 5) {
    A = Abase; lda = IN_PAD;
    Bt = Bbase; ldb = IN_PAD;
    kend = IN_PAD;
  } else {
    A = Abase; lda = 512;
    Bt = Bbase; ldb = 512;
    kend = 512;
  }

  const int tid = threadIdx.x;
  constexpr int PASSES = TILE / 32;  // staging passes per matrix
  // staging: 32 rows/pass, 8 threads/row, 16B each; source col-slot XOR'ed by
  // row&7 so that LINEAR LDS dest + swizzled read = conflict-free (rule #21).
  const int trow = tid >> 3, tq = tid & 7;
  const int sq = tq ^ (trow & 7);
  const bf16* ags = A + (size_t)(bi * TILE + trow) * lda + sq * 8;
  const bf16* bgs = Bt + (size_t)(bj * TILE + trow) * ldb + sq * 8;

  __shared__ __align__(16) bf16 As[2][TILE * 64];
  __shared__ __align__(16) bf16 Bs[2][TILE * 64];
  const int so = tid * 8;  // wave-uniform base + lane*16B

  const int lane = tid & 63, wid = tid >> 6;
  const int wr = wid >> 1, wc = wid & 1;
  const int fr = lane & 15, fg = lane >> 4;
  const int axor = fr & 7;
  constexpr int MR = TILE / 32;  // fragment repeats per wave (4 or 2)

  f32x4 acc[MR][MR] = {};

  auto stage = [&](int buf, int kk) {
#pragma unroll
    for (int p = 0; p < PASSES; ++p) {
      gld16(ags + (size_t)(p * 32) * lda + kk, &As[buf][p * 2048 + so]);
      gld16(bgs + (size_t)(p * 32) * ldb + kk, &Bs[buf][p * 2048 + so]);
    }
  };

  const int nt = kend >> 6;
  stage(0, 0);

  for (int t = 0; t < nt; ++t) {
    const int cur = t & 1;
    if (t + 1 < nt) {
      stage(cur ^ 1, (t + 1) << 6);
      if constexpr (TILE == 128)
        asm volatile("s_waitcnt vmcnt(8)" ::: "memory");
      else
        asm volatile("s_waitcnt vmcnt(4)" ::: "memory");
    } else {
      asm volatile("s_waitcnt vmcnt(0)" ::: "memory");
    }
    __builtin_amdgcn_sched_barrier(0);
    __builtin_amdgcn_s_barrier();
    __builtin_amdgcn_sched_barrier(0);

    __builtin_amdgcn_s_setprio(1);
#pragma unroll
    for (int s = 0; s < 2; ++s) {
      bf16x8 af[MR], bfv[MR];
#pragma unroll
      for (int m = 0; m < MR; ++m)
        af[m] = *(const bf16x8*)(&As[cur][(wr * (TILE / 2) + m * 16 + fr) * 64 + (((s * 4 + fg) ^ axor) * 8)]);
#pragma unroll
      for (int n = 0; n < MR; ++n)
        bfv[n] = *(const bf16x8*)(&Bs[cur][(wc * (TILE / 2) + n * 16 + fr) * 64 + (((s * 4 + fg) ^ axor) * 8)]);
#pragma unroll
      for (int m = 0; m < MR; ++m)
#pragma unroll
        for (int n = 0; n < MR; ++n)
          acc[m][n] = __builtin_amdgcn_mfma_f32_16x16x32_bf16(af[m], bfv[n], acc[m][n], 0, 0, 0);
    }
    __builtin_amdgcn_s_setprio(0);

    asm volatile("s_waitcnt lgkmcnt(0)" ::: "memory");
    __builtin_amdgcn_sched_barrier(0);
    __builtin_amdgcn_s_barrier();
    __builtin_amdgcn_sched_barrier(0);
  }

#pragma unroll
  for (int m = 0; m < MR; ++m) {
#pragma unroll
    for (int n = 0; n < MR; ++n) {
#pragma unroll
      for (int j = 0; j < 4; ++j) {
        int r = bi * TILE + wr * (TILE / 2) + m * 16 + fg * 4 + j;
        int c = bj * TILE + wc * (TILE / 2) + n * 16 + fr;
        float v = acc[m][n][j];
        if constexpr (MODE == 0) {
          v = fmaxf(v, 0.f);
          bout[((size_t)bz * T_SEQ + r) * N_INT + c] = (bf16)v;
        } else if constexpr (MODE == 1) {
          bout[(size_t)bz * T_SEQ * T_SEQ + (size_t)r * T_SEQ + c] = (bf16)(c < r ? v : 0.f);
        } else if constexpr (MODE == 2) {
          bout[((size_t)bz * T_SEQ + r) * 512 + c] = (bf16)v;
        } else if constexpr (MODE == 3) {
          v = fmaxf(v, 0.f);
          float g = (float)aux[((size_t)bz * T_SEQ + r) * N_INT + c];
          bout[(size_t)r * 16384 + (size_t)bz * N_INT + c] = (bf16)(v * g);
        } else if constexpr (MODE == 4) {
          bout[((size_t)chunk << 19) + (size_t)r * 512 + c] = (bf16)v;
        } else if constexpr (MODE == 5) {
          fout[(size_t)r * 512 + c] = v + fbias[c];
        } else {
          if (c < OUT_DIM) fout[(size_t)r * OUT_DIM + c] = v + fbias[c];
        }
      }
    }
  }
}

// ---------- named wrappers (distinct rocprof rows) ----------
__global__ __launch_bounds__(256, 2) void g_hsp(const bf16* A, const bf16* B, bf16* o) {
  gemm_body<0, 8, 128>(A, B, nullptr, nullptr, nullptr, o);
}
__global__ __launch_bounds__(256, 4) void g_scores(const bf16* A, bf16* o) {
  gemm_body<1, 0, 64>(A, nullptr, nullptr, nullptr, nullptr, o);
}
__global__ __launch_bounds__(256, 4) void g_pv(const bf16* A, const bf16* B, bf16* o) {
  gemm_body<2, 16, 64>(A, B, nullptr, nullptr, nullptr, o);
}
__global__ __launch_bounds__(256, 2) void g_gate(const bf16* A, const bf16* B, const bf16* aux, bf16* o) {
  gemm_body<3, 8, 128>(A, B, aux, nullptr, nullptr, o);
}
__global__ __launch_bounds__(256, 2) void g_dec(const bf16* A, const bf16* B, bf16* o) {
  gemm_body<4, 8, 128>(A, B, nullptr, nullptr, nullptr, o);
}
__global__ __launch_bounds__(256, 2) void g_in(const bf16* A, const bf16* B, const float* bias, float* o) {
  gemm_body<5, 16, 128>(A, B, nullptr, bias, o, nullptr);
}
__global__ __launch_bounds__(256, 2) void g_out(const bf16* A, const bf16* B, const float* bias, float* o) {
  gemm_body<6, 16, 128>(A, B, nullptr, bias, o, nullptr);
}

// ---------- launch ----------
extern "C" void kernel_launch(void* const* d_in, const int* in_sizes, int n_in,
                              void* d_out, int out_size, void* d_ws, size_t ws_size,
                              hipStream_t stream) {
  const float* x = (const float*)d_in[0];
  const float* Wi = (const float*)d_in[1];
  const float* bi = (const float*)d_in[2];
  const float* enc = (const float*)d_in[3];
  const float* encv = (const float*)d_in[4];
  const float* dec = (const float*)d_in[5];
  const float* Wo = (const float*)d_in[6];
  const float* bo = (const float*)d_in[7];
  float* out = (float*)d_out;

  const size_t NEED = 163840000;
  if (ws_size < NEED) return;

  char* w = (char*)d_ws;
  auto alloc = [&](size_t bytes) {
    char* p = w;
    w += (bytes + 255) & ~(size_t)255;
    return p;
  };
  bf16* encT = (bf16*)alloc((size_t)NHEADS * N_INT * 512 * 2);
  bf16* encvT = (bf16*)alloc((size_t)NHEADS * N_INT * 512 * 2);
  bf16* decT = (bf16*)alloc((size_t)512 * 16384 * 2);
  float* cost = (float*)alloc((size_t)T_SEQ * 1024 * 4);
  float* sint = (float*)alloc((size_t)T_SEQ * 1024 * 4);
  float* h = (float*)alloc((size_t)2048 * 512 * 4);
  bf16* hbf = (bf16*)alloc((size_t)2048 * 512 * 2);
  bf16* hT = (bf16*)alloc((size_t)2048 * 512 * 2);
  bf16* hsp = (bf16*)alloc((size_t)NHEADS * T_SEQ * N_INT * 2);
  bf16* qr = (bf16*)alloc((size_t)NHEADS * T_SEQ * N_INT * 2);   // reused as xy
  bf16* S = (bf16*)alloc((size_t)NHEADS * T_SEQ * T_SEQ * 2);    // reused as dec partials
  bf16* ykv = (bf16*)alloc((size_t)NHEADS * T_SEQ * 512 * 2);
  float* zbuf = (float*)alloc((size_t)2048 * 512 * 4);
  bf16* WoT = (bf16*)alloc((size_t)OUT_PAD * 512 * 2);
  // xbf and WiT alias S (dead until first g_scores)
  bf16* xbf = S;
  bf16* WiT = S + 1048576;

  transpose_cvt<<<dim3(64, 16, 8), dim3(32, 8), 0, stream>>>(enc, encT, 512, N_INT);
  transpose_cvt<<<dim3(64, 16, 8), dim3(32, 8), 0, stream>>>(encv, encvT, 512, N_INT);
  transpose_cvt<<<dim3(16, 512, 1), dim3(32, 8), 0, stream>>>(dec, decT, 16384, 512);
  pad_trans<<<dim3(16, 12), dim3(32, 8), 0, stream>>>(Wi, WiT, IN_DIM, 512, IN_PAD);
  pad_trans<<<dim3(8, 16), dim3(32, 8), 0, stream>>>(Wo, WoT, 512, OUT_DIM, 512);
  cvt_pad_x<<<2048, 256, 0, stream>>>(x, xbf);
  rope_tables<<<1024, 256, 0, stream>>>(cost, sint);
  g_in<<<64, 256, 0, stream>>>(xbf, WiT, bi, zbuf);
  ln0<<<2048, 256, 0, stream>>>(zbuf, h, hbf, hT);

  for (int L = 0; L < 3; ++L) {
    for (int b = 0; b < 2; ++b) {
      const bf16* hbf_b = hbf + (size_t)b * T_SEQ * 512;
      const bf16* hT_b = hT + (size_t)b * 512 * T_SEQ;
      float* zbuf_b = zbuf + (size_t)b * T_SEQ * 512;
      g_hsp<<<1024, 256, 0, stream>>>(hbf_b, encT, hsp);
      rope_apply<<<4096, 256, 0, stream>>>(hsp, cost, sint, qr);
      g_scores<<<1088, 256, 0, stream>>>(qr, S);
      g_pv<<<1024, 256, 0, stream>>>(S, hT_b, ykv);
      ln_rows<<<8192, 256, 0, stream>>>(ykv);
      g_gate<<<1024, 256, 0, stream>>>(ykv, encvT, hsp, qr);
      g_dec<<<512, 256, 0, stream>>>(qr, decT, S);
      psum16<<<1024, 256, 0, stream>>>(S, zbuf_b);
    }
    ln_double<<<2048, 256, 0, stream>>>(zbuf, h, hbf, hT);
  }
  g_out<<<32, 256, 0, stream>>>(hbf, WoT, bo, out);
}